// Round 4
// baseline (489.567 us; speedup 1.0000x reference)
//
#include <hip/hip_runtime.h>

typedef unsigned long long u64;
typedef unsigned int u32;

#define BDIM 16
#define NP   4096
#define NC   91
#define NCM1 90
#define MSEL 4096     // top-M per image
#define KOUT 100
#define RSLOT 19      // max candidates per row (scores sum to 1, >0.05 => <=19)
#define SCORE_T 0.05f
#define NMS_T   0.5f
#define OFFSETF 10000.0f
#define DW_CLAMP_F 4.135166556742356f
#define WF 1333.0f
#define HF 800.0f

#define TN 256
#define SL (MSEL / TN)   // 16 register-resident candidates per thread
#define NW (TN / 64)     // 4 waves

// ---------------- Kernel 1: softmax + threshold -> per-row keys + count ----------------
__global__ __launch_bounds__(256) void k_softmax(const float* __restrict__ logits,
                                                 u64* __restrict__ keys,
                                                 int* __restrict__ rowcnt) {
    int row  = blockIdx.x * 4 + (threadIdx.x >> 6);   // one wave per row
    int lane = threadIdx.x & 63;
    const float* lg = logits + (long)row * NC;

    float v0 = lg[lane];
    float v1 = (lane < NC - 64) ? lg[64 + lane] : -3.0e38f;
    float mx = fmaxf(v0, v1);
#pragma unroll
    for (int s = 32; s; s >>= 1) mx = fmaxf(mx, __shfl_xor(mx, s));
    float e0 = expf(v0 - mx);
    float e1 = (lane < NC - 64) ? expf(v1 - mx) : 0.0f;
    float sum = e0 + e1;
#pragma unroll
    for (int s = 32; s; s >>= 1) sum += __shfl_xor(sum, s);

    float s0 = e0 / sum;
    float s1 = e1 / sum;

    int b = row >> 12;          // / NP
    int n = row & (NP - 1);

    bool p0 = (lane >= 1) && (s0 > SCORE_T);          // class = lane (skip background 0)
    bool p1 = (lane < NC - 64) && (s1 > SCORE_T);     // class = 64 + lane
    u64 m0 = __ballot(p0);
    u64 m1 = __ballot(p1);
    int c0  = __popcll(m0);
    int cnt = c0 + __popcll(m1);

    u64 lanemask = (1ull << lane) - 1ull;
    u64* kb = keys + ((long)b * NP + n) * RSLOT;
    if (p0) {
        int pos  = __popcll(m0 & lanemask);
        int flat = n * NCM1 + (lane - 1);
        kb[pos] = ((u64)__float_as_uint(s0) << 32) | (u32)(~(u32)flat);
    }
    if (p1) {
        int pos  = c0 + __popcll(m1 & lanemask);
        int flat = n * NCM1 + (64 + lane - 1);
        kb[pos] = ((u64)__float_as_uint(s1) << 32) | (u32)(~(u32)flat);
    }
    if (lane == 0) rowcnt[row] = cnt;
}

// ---------------- radix-select pass (MSD), per-wave privatized histograms ----------------
template<int NB>
__device__ __forceinline__ void radix_pass(const u64* __restrict__ kb,
                                           const int* __restrict__ rc,
                                           int* ph, int* hist, int* s_wt,
                                           int* p_sel, int* p_gt,
                                           int tid, int lane, int wid, int shift,
                                           u64& prefix, u64& mask, int& rank) {
    constexpr int BPT = NB / TN;
    // zero private hists
    for (int i = tid; i < NW * NB; i += TN) ph[i] = 0;
    __syncthreads();
    // build (only candidates matching current prefix)
    int* myph = ph + wid * NB;
    for (int r = tid; r < NP; r += TN) {
        int cnt = rc[r];
        const u64* kr = kb + (long)r * RSLOT;
        for (int j = 0; j < cnt; ++j) {
            u64 k = kr[j];
            if ((k & mask) == prefix)
                atomicAdd(&myph[(int)((k >> shift) & (u64)(NB - 1))], 1);
        }
    }
    __syncthreads();
    // combine private hists
    for (int j = tid; j < NB; j += TN) {
        int s = 0;
#pragma unroll
        for (int w = 0; w < NW; ++w) s += ph[w * NB + j];
        hist[j] = s;
    }
    __syncthreads();
    // hierarchical suffix-sum (register + shfl), in place: hist[j] = #keys in bins >= j
    int base = tid * BPT;
    int v[BPT], sfx[BPT];
#pragma unroll
    for (int q = 0; q < BPT; ++q) v[q] = hist[base + q];
    int run = 0;
#pragma unroll
    for (int q = BPT - 1; q >= 0; --q) { run += v[q]; sfx[q] = run; }
    int S = run;
#pragma unroll
    for (int s = 1; s < 64; s <<= 1) { int o = __shfl_down(S, s); if (lane + s < 64) S += o; }
    if (lane == 0) s_wt[wid] = S;
    int excl = S - run;
    __syncthreads();
    int add2 = excl;
    for (int w = wid + 1; w < NW; ++w) add2 += s_wt[w];
#pragma unroll
    for (int q = 0; q < BPT; ++q) hist[base + q] = sfx[q] + add2;
    __syncthreads();
    // pick the unique bin with cum[j] >= rank > cum[j+1]
#pragma unroll
    for (int q = 0; q < BPT; ++q) {
        int j = base + q;
        int c  = hist[j];
        int cn = (j + 1 < NB) ? hist[j + 1] : 0;
        if (c >= rank && cn < rank) { *p_sel = j; *p_gt = cn; }
    }
    __syncthreads();
    prefix |= (u64)(*p_sel) << shift;
    mask   |= (u64)(NB - 1) << shift;
    rank   -= *p_gt;
    __syncthreads();
}

// ---------------- Kernel 2: select + gather + decode + greedy NMS (one block/image) ----------------
__global__ __launch_bounds__(TN, 1) void k_post(const u64* __restrict__ keys,
                                                const int* __restrict__ rowcnt,
                                                const float* __restrict__ boxreg,
                                                const float* __restrict__ props,
                                                float* __restrict__ out) {
    __shared__ u64 s_skey[MSEL];        // 32 KB; aliased as int ph[NW*2048] during select
    __shared__ int s_hist[2048];        // 8 KB
    __shared__ int s_wt[NW];
    __shared__ u64 s_wred[NW];
    __shared__ int s_sel, s_gt, s_cnt;
    __shared__ float4 s_obox;
    __shared__ float s_area;
    __shared__ int s_lab;

    int b = blockIdx.x, tid = threadIdx.x;
    int lane = tid & 63, wid = tid >> 6;
    const u64* kb = keys + (long)b * NP * RSLOT;
    const int* rc = rowcnt + b * NP;

    // ---- total candidate count ----
    int mycnt = 0;
    for (int r = tid; r < NP; r += TN) mycnt += rc[r];
#pragma unroll
    for (int s = 32; s; s >>= 1) mycnt += __shfl_xor(mycnt, s);
    if (lane == 0) s_wt[wid] = mycnt;
    __syncthreads();
    int ntot = 0;
#pragma unroll
    for (int w = 0; w < NW; ++w) ntot += s_wt[w];
    __syncthreads();

    // ---- exact threshold = MSEL-th largest key (keys distinct) ----
    u64 T = 0ull;
    if (ntot > MSEL) {
        int* ph = (int*)s_skey;
        u64 prefix = 0, mask = 0;
        int rank = MSEL;
        radix_pass<2048>(kb, rc, ph, s_hist, s_wt, &s_sel, &s_gt, tid, lane, wid, 53, prefix, mask, rank);
        radix_pass<2048>(kb, rc, ph, s_hist, s_wt, &s_sel, &s_gt, tid, lane, wid, 42, prefix, mask, rank);
        radix_pass<1024>(kb, rc, ph, s_hist, s_wt, &s_sel, &s_gt, tid, lane, wid, 32, prefix, mask, rank);
        radix_pass<2048>(kb, rc, ph, s_hist, s_wt, &s_sel, &s_gt, tid, lane, wid, 21, prefix, mask, rank);
        radix_pass<2048>(kb, rc, ph, s_hist, s_wt, &s_sel, &s_gt, tid, lane, wid, 10, prefix, mask, rank);
        radix_pass<1024>(kb, rc, ph, s_hist, s_wt, &s_sel, &s_gt, tid, lane, wid,  0, prefix, mask, rank);
        T = prefix;
    }

    // ---- gather keys >= T into LDS (wave-aggregated) ----
    if (tid == 0) s_cnt = 0;
    __syncthreads();
    u64 lanemask = (1ull << lane) - 1ull;
    for (int r = tid; r < NP; r += TN) {      // NP % TN == 0
        int cnt = rc[r];
        const u64* kr = kb + (long)r * RSLOT;
        int j = 0;
        while (__ballot(j < cnt)) {
            u64 k = (j < cnt) ? kr[j] : 0ull;
            bool pred = (j < cnt) && (k >= T);
            u64 mb = __ballot(pred);
            int c2 = __popcll(mb);
            int bp = 0;
            if (lane == 0 && c2) bp = atomicAdd(&s_cnt, c2);
            bp = __shfl(bp, 0);
            if (pred) {
                int pos = bp + __popcll(mb & lanemask);
                if (pos < MSEL) s_skey[pos] = k;
            }
            ++j;
        }
    }
    __syncthreads();
    int m = s_cnt; if (m > MSEL) m = MSEL;

    // ---- pull owned candidates into registers; decode once ----
    u64 rkey[SL];
    float4 rraw[SL];     // clipped box (output)
    float4 robx[SL];     // class-offset box (NMS coords)
    float rarea[SL];
    int rlab[SL];
#pragma unroll
    for (int j = 0; j < SL; ++j) {
        int i = tid + j * TN;
        rkey[j] = (i < m) ? s_skey[i] : 0ull;
        if (rkey[j]) {
            u64 k = rkey[j];
            int flat = (int)(~(u32)k);
            int nidx = flat / NCM1;
            int c    = flat - nidx * NCM1 + 1;
            const float* pr = props + ((long)b * NP + nidx) * 4;
            float x1 = pr[0], y1 = pr[1], x2 = pr[2], y2 = pr[3];
            float w = x2 - x1, h = y2 - y1;
            float cx = x1 + 0.5f * w, cy = y1 + 0.5f * h;
            const float* rr = boxreg + (((long)b * NP + nidx) * NC + c) * 4;
            float dx = rr[0] / 10.0f, dy = rr[1] / 10.0f;
            float dw = fminf(rr[2] / 5.0f, DW_CLAMP_F);
            float dh = fminf(rr[3] / 5.0f, DW_CLAMP_F);
            // avoid FMA contraction: numpy does separate mul + add
            float pcx = __fadd_rn(__fmul_rn(dx, w), cx);
            float pcy = __fadd_rn(__fmul_rn(dy, h), cy);
            float pw = __fmul_rn(expf(dw), w);
            float ph2 = __fmul_rn(expf(dh), h);
            float bx1 = fminf(fmaxf(pcx - 0.5f * pw, 0.0f), WF);
            float by1 = fminf(fmaxf(pcy - 0.5f * ph2, 0.0f), HF);
            float bx2 = fminf(fmaxf(pcx + 0.5f * pw, 0.0f), WF);
            float by2 = fminf(fmaxf(pcy + 0.5f * ph2, 0.0f), HF);
            rraw[j] = make_float4(bx1, by1, bx2, by2);
            float offB = (float)c * OFFSETF;
            float ox1 = bx1 + offB, oy1 = by1 + offB;
            float ox2 = bx2 + offB, oy2 = by2 + offB;
            robx[j] = make_float4(ox1, oy1, ox2, oy2);
            rarea[j] = (ox2 - ox1) * (oy2 - oy1);
            rlab[j] = c;
        }
    }
    __syncthreads();

    // ---- greedy NMS: 2 barriers per iteration ----
    int kdone = KOUT;
    for (int k = 0; k < KOUT; ++k) {
        u64 best = 0;
#pragma unroll
        for (int j = 0; j < SL; ++j) if (rkey[j] > best) best = rkey[j];
#pragma unroll
        for (int s = 32; s; s >>= 1) { u64 o = __shfl_xor(best, s); if (o > best) best = o; }
        if (lane == 0) s_wred[wid] = best;
        __syncthreads();
        u64 ball = s_wred[0];
#pragma unroll
        for (int w = 1; w < NW; ++w) { u64 o = s_wred[w]; if (o > ball) ball = o; }
        if (ball == 0ull) { kdone = k; break; }   // uniform across block

        float scoreA = __uint_as_float((u32)(ball >> 32));
#pragma unroll
        for (int j = 0; j < SL; ++j) {
            if (rkey[j] == ball) {               // unique winner (keys distinct)
                s_obox = robx[j]; s_area = rarea[j]; s_lab = rlab[j];
                rkey[j] = 0ull;
                float* ob = out + ((long)b * KOUT + k) * 4;
                ob[0] = rraw[j].x; ob[1] = rraw[j].y; ob[2] = rraw[j].z; ob[3] = rraw[j].w;
                out[BDIM * KOUT * 4 + b * KOUT + k] = scoreA;
                out[BDIM * KOUT * 5 + b * KOUT + k] = (float)rlab[j];
                out[BDIM * KOUT * 6 + b * KOUT + k] = 1.0f;
            }
        }
        __syncthreads();
        float4 A = s_obox;
        float areaA = s_area;
        int labA = s_lab;

        // suppression: cross-class IoU is exactly 0 -> label gate
#pragma unroll
        for (int j = 0; j < SL; ++j) {
            if (rkey[j] && rlab[j] == labA) {
                float4 Bv = robx[j];
                float iw = fmaxf(fminf(A.z, Bv.z) - fmaxf(A.x, Bv.x), 0.0f);
                float ih = fmaxf(fminf(A.w, Bv.w) - fmaxf(A.y, Bv.y), 0.0f);
                float inter = iw * ih;
                float denom = rarea[j] + areaA - inter + 1e-9f;
                float iou = inter / denom;
                if (iou > NMS_T) rkey[j] = 0ull;
            }
        }
        // no barrier: next iter's s_wred write is ordered by this iter's 2nd barrier,
        // and s_obox readers are separated from the next write by the next 1st barrier.
    }

    // fill remaining slots as invalid
    for (int k = kdone + tid; k < KOUT; k += TN) {
        float* ob = out + ((long)b * KOUT + k) * 4;
        ob[0] = 0.0f; ob[1] = 0.0f; ob[2] = 0.0f; ob[3] = 0.0f;
        out[BDIM * KOUT * 4 + b * KOUT + k] = 0.0f;
        out[BDIM * KOUT * 5 + b * KOUT + k] = -1.0f;
        out[BDIM * KOUT * 6 + b * KOUT + k] = 0.0f;
    }
}

extern "C" void kernel_launch(void* const* d_in, const int* in_sizes, int n_in,
                              void* d_out, int out_size, void* d_ws, size_t ws_size,
                              hipStream_t stream) {
    const float* logits = (const float*)d_in[0];
    const float* boxreg = (const float*)d_in[1];
    const float* props  = (const float*)d_in[2];
    float* out = (float*)d_out;

    char* ws = (char*)d_ws;
    int* rowcnt = (int*)ws;                       // 65536 * 4 = 256 KB
    u64* keys   = (u64*)(ws + 262144);            // 16 * 4096 * 19 * 8 = 9.96 MB

    k_softmax<<<(BDIM * NP) / 4, 256, 0, stream>>>(logits, keys, rowcnt);
    k_post<<<BDIM, TN, 0, stream>>>(keys, rowcnt, boxreg, props, out);
}

// Round 6
// 353.809 us; speedup vs baseline: 1.3837x; 1.3837x over previous
//
#include <hip/hip_runtime.h>

typedef unsigned long long u64;
typedef unsigned int u32;

#define BDIM 16
#define NP   4096
#define NC   91
#define NCM1 90
#define MSEL 4096       // top-M per image
#define KOUT 100
#define CAP_D 40960     // dense candidate cap per image (expected ~15K)
#define SCORE_T 0.05f
#define NMS_T   0.5f
#define OFFSETF 10000.0f
#define DW_CLAMP_F 4.135166556742356f
#define WF 1333.0f
#define HF 800.0f

#define TN 1024
#define SL (MSEL / TN)   // 4 register-resident candidates per thread
#define NW (TN / 64)     // 16 waves

// ---------------- softmax kernel: MODE 0 = count only, MODE 1 = emit keys ----------------
template<int EMIT>
__global__ __launch_bounds__(256) void k_soft(const float* __restrict__ logits,
                                              int* __restrict__ rowcnt,
                                              const int* __restrict__ rowoff,
                                              u64* __restrict__ dense) {
    int row  = blockIdx.x * 4 + (threadIdx.x >> 6);   // one wave per row
    int lane = threadIdx.x & 63;
    const float* lg = logits + (long)row * NC;

    float v0 = lg[lane];
    float v1 = (lane < NC - 64) ? lg[64 + lane] : -3.0e38f;
    float mx = fmaxf(v0, v1);
#pragma unroll
    for (int s = 32; s; s >>= 1) mx = fmaxf(mx, __shfl_xor(mx, s));
    float e0 = expf(v0 - mx);
    float e1 = (lane < NC - 64) ? expf(v1 - mx) : 0.0f;
    float sum = e0 + e1;
#pragma unroll
    for (int s = 32; s; s >>= 1) sum += __shfl_xor(sum, s);

    float s0 = e0 / sum;
    float s1 = e1 / sum;

    bool p0 = (lane >= 1) && (s0 > SCORE_T);          // class = lane (skip background 0)
    bool p1 = (lane < NC - 64) && (s1 > SCORE_T);     // class = 64 + lane
    u64 m0 = __ballot(p0);
    u64 m1 = __ballot(p1);
    int c0 = __popcll(m0);

    if (EMIT == 0) {
        if (lane == 0) rowcnt[row] = c0 + __popcll(m1);
    } else {
        int b = row >> 12;
        int n = row & (NP - 1);
        int off = rowoff[row];
        u64 lm = (1ull << lane) - 1ull;
        u64* kb = dense + (long)b * CAP_D;
        if (p0) {
            int pos  = off + __popcll(m0 & lm);
            int flat = n * NCM1 + (lane - 1);
            if (pos < CAP_D)
                kb[pos] = ((u64)__float_as_uint(s0) << 32) | (u32)(~(u32)flat);
        }
        if (p1) {
            int pos  = off + c0 + __popcll(m1 & lm);
            int flat = n * NCM1 + (64 + lane - 1);
            if (pos < CAP_D)
                kb[pos] = ((u64)__float_as_uint(s1) << 32) | (u32)(~(u32)flat);
        }
    }
}

// ---------------- per-image exclusive prefix scan of rowcnt -> rowoff, nsel ----------------
__global__ __launch_bounds__(1024) void k_scan(const int* __restrict__ rowcnt,
                                               int* __restrict__ rowoff,
                                               int* __restrict__ nsel) {
    __shared__ int s_wt[16];
    int b = blockIdx.x, tid = threadIdx.x;
    int lane = tid & 63, wid = tid >> 6;

    int4 c4 = *(const int4*)(rowcnt + (long)b * NP + tid * 4);
    int ts = c4.x + c4.y + c4.z + c4.w;
    int S = ts;
#pragma unroll
    for (int s = 1; s < 64; s <<= 1) { int o = __shfl_up(S, s); if (lane >= s) S += o; }
    if (lane == 63) s_wt[wid] = S;
    int exclw = S - ts;
    __syncthreads();
    int add = 0;
    for (int w = 0; w < wid; ++w) add += s_wt[w];
    int base = add + exclw;
    int* ro = rowoff + (long)b * NP + tid * 4;
    ro[0] = base;
    ro[1] = base + c4.x;
    ro[2] = base + c4.x + c4.y;
    ro[3] = base + c4.x + c4.y + c4.z;
    if (tid == 1023) nsel[b] = base + ts;
}

// ---------------- per-image radix select of the MSEL-th largest key ----------------
// (round-2/3-verified structure: single hist + doubling suffix-sum)
__global__ __launch_bounds__(1024) void k_select(const u64* __restrict__ dense,
                                                 const int* __restrict__ nsel,
                                                 u64* __restrict__ Tsel) {
    __shared__ int hist[2048];
    __shared__ int s_sel, s_gt;
    int b   = blockIdx.x;
    int tid = threadIdx.x;
    int n = nsel[b]; if (n > CAP_D) n = CAP_D;
    if (n <= MSEL) { if (tid == 0) Tsel[b] = 0ull; return; }

    const u64* kb = dense + (long)b * CAP_D;
    u64 prefix = 0, mask = 0;
    int rank = MSEL;                               // rank-th largest (1-indexed)
    const int shifts[6] = {53, 42, 31, 20, 10, 0};
    const int bitsv [6] = {11, 11, 11, 11, 10, 10};

    for (int pass = 0; pass < 6; ++pass) {
        int shift = shifts[pass];
        int nb = 1 << bitsv[pass];
        if (tid < nb) hist[tid] = 0;
        if (tid + 1024 < nb) hist[tid + 1024] = 0;
        __syncthreads();
        for (int i = tid; i < n; i += 1024) {
            u64 k = kb[i];
            if ((k & mask) == prefix)
                atomicAdd(&hist[(int)((k >> shift) & (u64)(nb - 1))], 1);
        }
        __syncthreads();
        // suffix sum: hist[j] = count of elements in bins >= j
        for (int d = 1; d < nb; d <<= 1) {
            int v0 = 0, v1 = 0;
            if (tid < nb && tid + d < nb) v0 = hist[tid + d];
            if (tid + 1024 < nb && tid + 1024 + d < nb) v1 = hist[tid + 1024 + d];
            __syncthreads();
            if (tid < nb) hist[tid] += v0;
            if (tid + 1024 < nb) hist[tid + 1024] += v1;
            __syncthreads();
        }
        // find the unique bin with cum[j] >= rank > cum[j+1]
        for (int j = tid; j < nb; j += 1024) {
            int c  = hist[j];
            int cn = (j + 1 < nb) ? hist[j + 1] : 0;
            if (c >= rank && cn < rank) { s_sel = j; s_gt = cn; }
        }
        __syncthreads();
        prefix |= ((u64)s_sel) << shift;
        mask   |= ((u64)(nb - 1)) << shift;
        rank   -= s_gt;
        __syncthreads();
    }
    if (tid == 0) Tsel[b] = prefix;
}

// ---------------- gather + decode + greedy NMS (LDS boxes, no spill) ----------------
__global__ __launch_bounds__(TN) void k_nms(const u64* __restrict__ dense,
                                            const int* __restrict__ nsel,
                                            const u64* __restrict__ Tsel,
                                            const float* __restrict__ boxreg,
                                            const float* __restrict__ props,
                                            float* __restrict__ out) {
    __shared__ u64 skey[MSEL];          // 32 KB staging for compacted keys
    __shared__ float4 sbox[MSEL];       // 64 KB raw clipped boxes
    __shared__ u64 wred[NW];
    __shared__ int s_cnt, s_wpos, s_lab;
    __shared__ float s_area;

    int b = blockIdx.x, tid = threadIdx.x;
    int lane = tid & 63, wid = tid >> 6;
    int n = nsel[b]; if (n > CAP_D) n = CAP_D;
    u64 T = Tsel[b];
    const u64* kb = dense + (long)b * CAP_D;

    if (tid == 0) s_cnt = 0;
    __syncthreads();

    // wave-aggregated gather of keys >= T (exactly min(n, MSEL) of them)
    u64 lm = (1ull << lane) - 1ull;
    int npad = (n + TN - 1) & ~(TN - 1);
    for (int i0 = tid; i0 < npad; i0 += TN) {
        bool inb = (i0 < n);
        u64 k = inb ? kb[i0] : 0ull;
        bool pred = inb && (k >= T);
        u64 mb = __ballot(pred);
        int cnt = __popcll(mb);
        int bp = 0;
        if (lane == 0 && cnt) bp = atomicAdd(&s_cnt, cnt);
        bp = __shfl(bp, 0);
        if (pred) {
            int pos = bp + __popcll(mb & lm);
            if (pos < MSEL) skey[pos] = k;
        }
    }
    __syncthreads();
    int m = s_cnt; if (m > MSEL) m = MSEL;

    // decode: keys/areas/labels -> registers (16 VGPRs), raw boxes -> LDS
    u64 rkey[SL];
    float rarea[SL];
    int rlab[SL];
#pragma unroll
    for (int j = 0; j < SL; ++j) {
        int i = tid + j * TN;
        rkey[j] = (i < m) ? skey[i] : 0ull;
        rarea[j] = 0.0f; rlab[j] = -1;
        if (rkey[j]) {
            u64 k = rkey[j];
            int flat = (int)(~(u32)k);
            int nidx = flat / NCM1;
            int c    = flat - nidx * NCM1 + 1;
            const float* pr = props + ((long)b * NP + nidx) * 4;
            float x1 = pr[0], y1 = pr[1], x2 = pr[2], y2 = pr[3];
            float w = x2 - x1, h = y2 - y1;
            float cx = x1 + 0.5f * w, cy = y1 + 0.5f * h;
            const float* rr = boxreg + (((long)b * NP + nidx) * NC + c) * 4;
            float dx = rr[0] / 10.0f, dy = rr[1] / 10.0f;
            float dw = fminf(rr[2] / 5.0f, DW_CLAMP_F);
            float dh = fminf(rr[3] / 5.0f, DW_CLAMP_F);
            // avoid FMA contraction: numpy does separate mul + add
            float pcx = __fadd_rn(__fmul_rn(dx, w), cx);
            float pcy = __fadd_rn(__fmul_rn(dy, h), cy);
            float pw  = __fmul_rn(expf(dw), w);
            float ph2 = __fmul_rn(expf(dh), h);
            float bx1 = fminf(fmaxf(pcx - 0.5f * pw, 0.0f), WF);
            float by1 = fminf(fmaxf(pcy - 0.5f * ph2, 0.0f), HF);
            float bx2 = fminf(fmaxf(pcx + 0.5f * pw, 0.0f), WF);
            float by2 = fminf(fmaxf(pcy + 0.5f * ph2, 0.0f), HF);
            sbox[i] = make_float4(bx1, by1, bx2, by2);
            // area on class-offset coords, exactly as reference computes it
            float offB = (float)c * OFFSETF;
            float ox1 = bx1 + offB, oy1 = by1 + offB;
            float ox2 = bx2 + offB, oy2 = by2 + offB;
            rarea[j] = (ox2 - ox1) * (oy2 - oy1);
            rlab[j] = c;
        }
    }
    __syncthreads();

    // greedy NMS: 2 barriers per iteration (round-4-verified structure)
    int kdone = KOUT;
    for (int k = 0; k < KOUT; ++k) {
        u64 best = 0;
#pragma unroll
        for (int j = 0; j < SL; ++j) if (rkey[j] > best) best = rkey[j];
#pragma unroll
        for (int s = 32; s; s >>= 1) { u64 o = __shfl_xor(best, s); if (o > best) best = o; }
        if (lane == 0) wred[wid] = best;
        __syncthreads();
        u64 ball = wred[0];
#pragma unroll
        for (int w = 1; w < NW; ++w) { u64 o = wred[w]; if (o > ball) ball = o; }
        if (ball == 0ull) { kdone = k; break; }   // uniform across block

        float scoreA = __uint_as_float((u32)(ball >> 32));
#pragma unroll
        for (int j = 0; j < SL; ++j) {
            if (rkey[j] == ball) {               // unique winner (keys distinct)
                int i = tid + j * TN;
                s_wpos = i; s_area = rarea[j]; s_lab = rlab[j];
                rkey[j] = 0ull;
                float4 bb = sbox[i];
                float* ob = out + ((long)b * KOUT + k) * 4;
                ob[0] = bb.x; ob[1] = bb.y; ob[2] = bb.z; ob[3] = bb.w;
                out[BDIM * KOUT * 4 + b * KOUT + k] = scoreA;
                out[BDIM * KOUT * 5 + b * KOUT + k] = (float)rlab[j];
                out[BDIM * KOUT * 6 + b * KOUT + k] = 1.0f;
            }
        }
        __syncthreads();
        int wpos = s_wpos;
        float4 A = sbox[wpos];                   // raw box of winner (LDS broadcast)
        float areaA = s_area;
        int labA = s_lab;
        float offA = (float)labA * OFFSETF;

        // suppression: cross-class IoU is exactly 0 -> label gate.
        // offset coords recomputed per-IoU: rnd(min(rawA,rawB)+off) ==
        // min(rnd(rawA+off), rnd(rawB+off)) by rounding monotonicity -> bit-exact.
#pragma unroll
        for (int j = 0; j < SL; ++j) {
            if (rkey[j] && rlab[j] == labA) {
                float4 Bv = sbox[tid + j * TN];
                float op1x = __fadd_rn(fminf(A.z, Bv.z), offA);
                float op2x = __fadd_rn(fmaxf(A.x, Bv.x), offA);
                float iw = fmaxf(op1x - op2x, 0.0f);
                float op1y = __fadd_rn(fminf(A.w, Bv.w), offA);
                float op2y = __fadd_rn(fmaxf(A.y, Bv.y), offA);
                float ih = fmaxf(op1y - op2y, 0.0f);
                float inter = iw * ih;
                float denom = rarea[j] + areaA - inter + 1e-9f;
                float iou = inter / denom;
                if (iou > NMS_T) rkey[j] = 0ull;
            }
        }
        // no barrier: next iter's wred write comes after this iter's 2nd barrier,
        // and sbox/s_* reads above are separated from the next writes by barriers.
    }

    // fill remaining slots as invalid
    for (int k = kdone + tid; k < KOUT; k += TN) {
        float* ob = out + ((long)b * KOUT + k) * 4;
        ob[0] = 0.0f; ob[1] = 0.0f; ob[2] = 0.0f; ob[3] = 0.0f;
        out[BDIM * KOUT * 4 + b * KOUT + k] = 0.0f;
        out[BDIM * KOUT * 5 + b * KOUT + k] = -1.0f;
        out[BDIM * KOUT * 6 + b * KOUT + k] = 0.0f;
    }
}

extern "C" void kernel_launch(void* const* d_in, const int* in_sizes, int n_in,
                              void* d_out, int out_size, void* d_ws, size_t ws_size,
                              hipStream_t stream) {
    const float* logits = (const float*)d_in[0];
    const float* boxreg = (const float*)d_in[1];
    const float* props  = (const float*)d_in[2];
    float* out = (float*)d_out;

    char* ws = (char*)d_ws;
    int* rowcnt = (int*)(ws + 0);                 // 256 KB
    int* rowoff = (int*)(ws + 262144);            // 256 KB
    int* nsel   = (int*)(ws + 524288);            // 64 B
    u64* Tsel   = (u64*)(ws + 525312);            // 128 B
    u64* dense  = (u64*)(ws + 526336);            // 16*40960*8 = 5.24 MB -> total ~5.77 MB

    k_soft<0><<<(BDIM * NP) / 4, 256, 0, stream>>>(logits, rowcnt, nullptr, nullptr);
    k_scan<<<BDIM, 1024, 0, stream>>>(rowcnt, rowoff, nsel);
    k_soft<1><<<(BDIM * NP) / 4, 256, 0, stream>>>(logits, rowcnt, rowoff, dense);
    k_select<<<BDIM, 1024, 0, stream>>>(dense, nsel, Tsel);
    k_nms<<<BDIM, TN, 0, stream>>>(dense, nsel, Tsel, boxreg, props, out);
}

// Round 7
// 210.246 us; speedup vs baseline: 2.3285x; 1.6828x over previous
//
#include <hip/hip_runtime.h>

typedef unsigned long long u64;
typedef unsigned int u32;
typedef unsigned char u8;

#define BDIM 16
#define NP   4096
#define NC   91
#define NCM1 90
#define MSEL 4096       // top-M per image
#define KOUT 100
#define CAP_D 40960     // dense candidate cap per image (expected ~15K)
#define SCORE_T 0.05f
#define NMS_T   0.5f
#define OFFSETF 10000.0f
#define DW_CLAMP_F 4.135166556742356f
#define WF 1333.0f
#define HF 800.0f

#define TN 1024
#define NW (TN / 64)     // 16 waves

// ---------------- softmax kernel: MODE 0 = count only, MODE 1 = emit keys ----------------
template<int EMIT>
__global__ __launch_bounds__(256) void k_soft(const float* __restrict__ logits,
                                              int* __restrict__ rowcnt,
                                              const int* __restrict__ rowoff,
                                              u64* __restrict__ dense) {
    int row  = blockIdx.x * 4 + (threadIdx.x >> 6);   // one wave per row
    int lane = threadIdx.x & 63;
    const float* lg = logits + (long)row * NC;

    float v0 = lg[lane];
    float v1 = (lane < NC - 64) ? lg[64 + lane] : -3.0e38f;
    float mx = fmaxf(v0, v1);
#pragma unroll
    for (int s = 32; s; s >>= 1) mx = fmaxf(mx, __shfl_xor(mx, s));
    float e0 = expf(v0 - mx);
    float e1 = (lane < NC - 64) ? expf(v1 - mx) : 0.0f;
    float sum = e0 + e1;
#pragma unroll
    for (int s = 32; s; s >>= 1) sum += __shfl_xor(sum, s);

    float s0 = e0 / sum;
    float s1 = e1 / sum;

    bool p0 = (lane >= 1) && (s0 > SCORE_T);          // class = lane (skip background 0)
    bool p1 = (lane < NC - 64) && (s1 > SCORE_T);     // class = 64 + lane
    u64 m0 = __ballot(p0);
    u64 m1 = __ballot(p1);
    int c0 = __popcll(m0);

    if (EMIT == 0) {
        if (lane == 0) rowcnt[row] = c0 + __popcll(m1);
    } else {
        int b = row >> 12;
        int n = row & (NP - 1);
        int off = rowoff[row];
        u64 lm = (1ull << lane) - 1ull;
        u64* kb = dense + (long)b * CAP_D;
        if (p0) {
            int pos  = off + __popcll(m0 & lm);
            int flat = n * NCM1 + (lane - 1);
            if (pos < CAP_D)
                kb[pos] = ((u64)__float_as_uint(s0) << 32) | (u32)(~(u32)flat);
        }
        if (p1) {
            int pos  = off + c0 + __popcll(m1 & lm);
            int flat = n * NCM1 + (64 + lane - 1);
            if (pos < CAP_D)
                kb[pos] = ((u64)__float_as_uint(s1) << 32) | (u32)(~(u32)flat);
        }
    }
}

// ---------------- per-image exclusive prefix scan of rowcnt -> rowoff, nsel ----------------
__global__ __launch_bounds__(1024) void k_scan(const int* __restrict__ rowcnt,
                                               int* __restrict__ rowoff,
                                               int* __restrict__ nsel) {
    __shared__ int s_wt[16];
    int b = blockIdx.x, tid = threadIdx.x;
    int lane = tid & 63, wid = tid >> 6;

    int4 c4 = *(const int4*)(rowcnt + (long)b * NP + tid * 4);
    int ts = c4.x + c4.y + c4.z + c4.w;
    int S = ts;
#pragma unroll
    for (int s = 1; s < 64; s <<= 1) { int o = __shfl_up(S, s); if (lane >= s) S += o; }
    if (lane == 63) s_wt[wid] = S;
    int exclw = S - ts;
    __syncthreads();
    int add = 0;
    for (int w = 0; w < wid; ++w) add += s_wt[w];
    int base = add + exclw;
    int* ro = rowoff + (long)b * NP + tid * 4;
    ro[0] = base;
    ro[1] = base + c4.x;
    ro[2] = base + c4.x + c4.y;
    ro[3] = base + c4.x + c4.y + c4.z;
    if (tid == 1023) nsel[b] = base + ts;
}

// ---------------- per-image radix select of the MSEL-th largest key ----------------
__global__ __launch_bounds__(1024) void k_select(const u64* __restrict__ dense,
                                                 const int* __restrict__ nsel,
                                                 u64* __restrict__ Tsel) {
    __shared__ int hist[2048];
    __shared__ int s_sel, s_gt;
    int b   = blockIdx.x;
    int tid = threadIdx.x;
    int n = nsel[b]; if (n > CAP_D) n = CAP_D;
    if (n <= MSEL) { if (tid == 0) Tsel[b] = 0ull; return; }

    const u64* kb = dense + (long)b * CAP_D;
    u64 prefix = 0, mask = 0;
    int rank = MSEL;                               // rank-th largest (1-indexed)
    const int shifts[6] = {53, 42, 31, 20, 10, 0};
    const int bitsv [6] = {11, 11, 11, 11, 10, 10};

    for (int pass = 0; pass < 6; ++pass) {
        int shift = shifts[pass];
        int nb = 1 << bitsv[pass];
        if (tid < nb) hist[tid] = 0;
        if (tid + 1024 < nb) hist[tid + 1024] = 0;
        __syncthreads();
        for (int i = tid; i < n; i += 1024) {
            u64 k = kb[i];
            if ((k & mask) == prefix)
                atomicAdd(&hist[(int)((k >> shift) & (u64)(nb - 1))], 1);
        }
        __syncthreads();
        // suffix sum: hist[j] = count of elements in bins >= j
        for (int d = 1; d < nb; d <<= 1) {
            int v0 = 0, v1 = 0;
            if (tid < nb && tid + d < nb) v0 = hist[tid + d];
            if (tid + 1024 < nb && tid + 1024 + d < nb) v1 = hist[tid + 1024 + d];
            __syncthreads();
            if (tid < nb) hist[tid] += v0;
            if (tid + 1024 < nb) hist[tid + 1024] += v1;
            __syncthreads();
        }
        for (int j = tid; j < nb; j += 1024) {
            int c  = hist[j];
            int cn = (j + 1 < nb) ? hist[j + 1] : 0;
            if (c >= rank && cn < rank) { s_sel = j; s_gt = cn; }
        }
        __syncthreads();
        prefix |= ((u64)s_sel) << shift;
        mask   |= ((u64)(nb - 1)) << shift;
        rank   -= s_gt;
        __syncthreads();
    }
    if (tid == 0) Tsel[b] = prefix;
}

// ---------------- gather + bitonic sort + decode + sorted-walk NMS ----------------
__global__ __launch_bounds__(TN) void k_nms(const u64* __restrict__ dense,
                                            const int* __restrict__ nsel,
                                            const u64* __restrict__ Tsel,
                                            const float* __restrict__ boxreg,
                                            const float* __restrict__ props,
                                            float* __restrict__ out) {
    __shared__ u64 skey[MSEL];          // 32 KB keys (sorted desc)
    __shared__ float4 sbox[MSEL];       // 64 KB raw clipped boxes
    __shared__ float sarea[MSEL];       // 16 KB offset-coordinate areas
    __shared__ u8 slab[MSEL];           // 4 KB labels
    // accepted list (written by walk wave, read by all at emit)
    __shared__ float aax1[KOUT], aay1[KOUT], aax2[KOUT], aay2[KOUT];
    __shared__ float aarea_s[KOUT];
    __shared__ int alab_s[KOUT];
    __shared__ u64 akey_s[KOUT];
    __shared__ int s_cnt, s_nacc;

    int b = blockIdx.x, tid = threadIdx.x;
    int lane = tid & 63;
    int n = nsel[b]; if (n > CAP_D) n = CAP_D;
    u64 T = Tsel[b];
    const u64* kb = dense + (long)b * CAP_D;

    if (tid == 0) s_cnt = 0;
    for (int i = tid; i < MSEL; i += TN) skey[i] = 0ull;
    __syncthreads();

    // ---- wave-aggregated gather of keys >= T (round-6 verified) ----
    u64 lm = (1ull << lane) - 1ull;
    int npad = (n + TN - 1) & ~(TN - 1);
    for (int i0 = tid; i0 < npad; i0 += TN) {
        bool inb = (i0 < n);
        u64 k = inb ? kb[i0] : 0ull;
        bool pred = inb && (k >= T);
        u64 mb = __ballot(pred);
        int cnt = __popcll(mb);
        int bp = 0;
        if (lane == 0 && cnt) bp = atomicAdd(&s_cnt, cnt);
        bp = __shfl(bp, 0);
        if (pred) {
            int pos = bp + __popcll(mb & lm);
            if (pos < MSEL) skey[pos] = k;
        }
    }
    __syncthreads();
    int m = s_cnt; if (m > MSEL) m = MSEL;

    // ---- bitonic sort descending over skey[0..MSEL) (zeros sink to the end) ----
    for (int kk = 2; kk <= MSEL; kk <<= 1) {
        for (int j = kk >> 1; j > 0; j >>= 1) {
            for (int t = tid; t < MSEL; t += TN) {
                int l = t ^ j;
                if (l > t) {
                    u64 a = skey[t], c = skey[l];
                    bool up = ((t & kk) == 0);
                    bool sw = up ? (a < c) : (a > c);   // descending sort
                    if (sw) { skey[t] = c; skey[l] = a; }
                }
            }
            __syncthreads();
        }
    }

    // ---- decode sorted candidates into LDS (round-6 verified expressions) ----
    for (int i = tid; i < m; i += TN) {
        u64 k = skey[i];
        int flat = (int)(~(u32)k);
        int nidx = flat / NCM1;
        int c    = flat - nidx * NCM1 + 1;
        const float* pr = props + ((long)b * NP + nidx) * 4;
        float x1 = pr[0], y1 = pr[1], x2 = pr[2], y2 = pr[3];
        float w = x2 - x1, h = y2 - y1;
        float cx = x1 + 0.5f * w, cy = y1 + 0.5f * h;
        const float* rr = boxreg + (((long)b * NP + nidx) * NC + c) * 4;
        float dx = rr[0] / 10.0f, dy = rr[1] / 10.0f;
        float dw = fminf(rr[2] / 5.0f, DW_CLAMP_F);
        float dh = fminf(rr[3] / 5.0f, DW_CLAMP_F);
        // avoid FMA contraction: numpy does separate mul + add
        float pcx = __fadd_rn(__fmul_rn(dx, w), cx);
        float pcy = __fadd_rn(__fmul_rn(dy, h), cy);
        float pw  = __fmul_rn(expf(dw), w);
        float ph2 = __fmul_rn(expf(dh), h);
        float bx1 = fminf(fmaxf(pcx - 0.5f * pw, 0.0f), WF);
        float by1 = fminf(fmaxf(pcy - 0.5f * ph2, 0.0f), HF);
        float bx2 = fminf(fmaxf(pcx + 0.5f * pw, 0.0f), WF);
        float by2 = fminf(fmaxf(pcy + 0.5f * ph2, 0.0f), HF);
        sbox[i] = make_float4(bx1, by1, bx2, by2);
        // area on class-offset coords, exactly as reference computes it
        float offB = (float)c * OFFSETF;
        float ox1 = bx1 + offB, oy1 = by1 + offB;
        float ox2 = bx2 + offB, oy2 = by2 + offB;
        sarea[i] = (ox2 - ox1) * (oy2 - oy1);
        slab[i] = (u8)c;
    }
    __syncthreads();

    // ---- serial walk in sorted order (wave 0 only, no block barriers) ----
    // Accept candidate iff no accepted same-class box has IoU > NMS_T.
    // Identical survivor sequence to greedy NMS (same IoU operands/compares).
    if (tid < 64) {
        volatile float* vx1 = aax1; volatile float* vy1 = aay1;
        volatile float* vx2 = aax2; volatile float* vy2 = aay2;
        volatile float* var = aarea_s;
        volatile int*   vlb = alab_s;
        int nacc = 0;
        for (int i = 0; i < m && nacc < KOUT; ++i) {
            int lab = (int)slab[i];
            float4 Bv = sbox[i];
            float areaB = sarea[i];
            float off = (float)lab * OFFSETF;
            bool conf = false;
            for (int a = lane; a < nacc; a += 64) {
                if (vlb[a] == lab) {
                    // offset coords recomputed: rnd(min(rawA,rawB)+off) ==
                    // min(rnd(rawA+off), rnd(rawB+off)) by rounding monotonicity
                    float op1x = __fadd_rn(fminf(vx2[a], Bv.z), off);
                    float op2x = __fadd_rn(fmaxf(vx1[a], Bv.x), off);
                    float iw = fmaxf(op1x - op2x, 0.0f);
                    float op1y = __fadd_rn(fminf(vy2[a], Bv.w), off);
                    float op2y = __fadd_rn(fmaxf(vy1[a], Bv.y), off);
                    float ih = fmaxf(op1y - op2y, 0.0f);
                    float inter = iw * ih;
                    float denom = areaB + var[a] - inter + 1e-9f;
                    float iou = inter / denom;
                    if (iou > NMS_T) conf = true;
                }
            }
            if (__ballot(conf) == 0ull) {        // uniform accept
                if (lane == 0) {
                    vx1[nacc] = Bv.x; vy1[nacc] = Bv.y;
                    vx2[nacc] = Bv.z; vy2[nacc] = Bv.w;
                    var[nacc] = areaB; vlb[nacc] = lab;
                    akey_s[nacc] = skey[i];
                }
                __builtin_amdgcn_wave_barrier();
                asm volatile("s_waitcnt lgkmcnt(0)" ::: "memory");
                ++nacc;
            }
        }
        if (lane == 0) s_nacc = nacc;
    }
    __syncthreads();

    // ---- emit outputs in acceptance order ----
    int nacc = s_nacc;
    if (tid < KOUT) {
        if (tid < nacc) {
            float* ob = out + ((long)b * KOUT + tid) * 4;
            ob[0] = aax1[tid]; ob[1] = aay1[tid]; ob[2] = aax2[tid]; ob[3] = aay2[tid];
            out[BDIM * KOUT * 4 + b * KOUT + tid] = __uint_as_float((u32)(akey_s[tid] >> 32));
            out[BDIM * KOUT * 5 + b * KOUT + tid] = (float)alab_s[tid];
            out[BDIM * KOUT * 6 + b * KOUT + tid] = 1.0f;
        } else {
            float* ob = out + ((long)b * KOUT + tid) * 4;
            ob[0] = 0.0f; ob[1] = 0.0f; ob[2] = 0.0f; ob[3] = 0.0f;
            out[BDIM * KOUT * 4 + b * KOUT + tid] = 0.0f;
            out[BDIM * KOUT * 5 + b * KOUT + tid] = -1.0f;
            out[BDIM * KOUT * 6 + b * KOUT + tid] = 0.0f;
        }
    }
}

extern "C" void kernel_launch(void* const* d_in, const int* in_sizes, int n_in,
                              void* d_out, int out_size, void* d_ws, size_t ws_size,
                              hipStream_t stream) {
    const float* logits = (const float*)d_in[0];
    const float* boxreg = (const float*)d_in[1];
    const float* props  = (const float*)d_in[2];
    float* out = (float*)d_out;

    char* ws = (char*)d_ws;
    int* rowcnt = (int*)(ws + 0);                 // 256 KB
    int* rowoff = (int*)(ws + 262144);            // 256 KB
    int* nsel   = (int*)(ws + 524288);            // 64 B
    u64* Tsel   = (u64*)(ws + 525312);            // 128 B
    u64* dense  = (u64*)(ws + 526336);            // 16*40960*8 = 5.24 MB

    k_soft<0><<<(BDIM * NP) / 4, 256, 0, stream>>>(logits, rowcnt, nullptr, nullptr);
    k_scan<<<BDIM, 1024, 0, stream>>>(rowcnt, rowoff, nsel);
    k_soft<1><<<(BDIM * NP) / 4, 256, 0, stream>>>(logits, rowcnt, rowoff, dense);
    k_select<<<BDIM, 1024, 0, stream>>>(dense, nsel, Tsel);
    k_nms<<<BDIM, TN, 0, stream>>>(dense, nsel, Tsel, boxreg, props, out);
}

// Round 8
// 114.996 us; speedup vs baseline: 4.2572x; 1.8283x over previous
//
#include <hip/hip_runtime.h>

typedef unsigned long long u64;
typedef unsigned int u32;

#define BDIM 16
#define NP   4096
#define NC   91
#define NCM1 90
#define MSEL 4096       // top-M per image (reference M)
#define NSORT 1024      // batch-0 sorted prefix size
#define KOUT 100
#define CAP_D 40960     // dense candidate cap per image (expected ~15K)
#define SCORE_T 0.05f
#define NMS_T   0.5f
#define OFFSETF 10000.0f
#define DW_CLAMP_F 4.135166556742356f
#define WF 1333.0f
#define HF 800.0f

#define TN 1024
#define NW (TN / 64)     // 16 waves

// ---------------- softmax kernel: MODE 0 = count only, MODE 1 = emit keys ----------------
template<int EMIT>
__global__ __launch_bounds__(256) void k_soft(const float* __restrict__ logits,
                                              int* __restrict__ rowcnt,
                                              const int* __restrict__ rowoff,
                                              u64* __restrict__ dense) {
    int row  = blockIdx.x * 4 + (threadIdx.x >> 6);   // one wave per row
    int lane = threadIdx.x & 63;
    const float* lg = logits + (long)row * NC;

    float v0 = lg[lane];
    float v1 = (lane < NC - 64) ? lg[64 + lane] : -3.0e38f;
    float mx = fmaxf(v0, v1);
#pragma unroll
    for (int s = 32; s; s >>= 1) mx = fmaxf(mx, __shfl_xor(mx, s));
    float e0 = expf(v0 - mx);
    float e1 = (lane < NC - 64) ? expf(v1 - mx) : 0.0f;
    float sum = e0 + e1;
#pragma unroll
    for (int s = 32; s; s >>= 1) sum += __shfl_xor(sum, s);

    float s0 = e0 / sum;
    float s1 = e1 / sum;

    bool p0 = (lane >= 1) && (s0 > SCORE_T);          // class = lane (skip background 0)
    bool p1 = (lane < NC - 64) && (s1 > SCORE_T);     // class = 64 + lane
    u64 m0 = __ballot(p0);
    u64 m1 = __ballot(p1);
    int c0 = __popcll(m0);

    if (EMIT == 0) {
        if (lane == 0) rowcnt[row] = c0 + __popcll(m1);
    } else {
        int b = row >> 12;
        int n = row & (NP - 1);
        int off = rowoff[row];
        u64 lm = (1ull << lane) - 1ull;
        u64* kb = dense + (long)b * CAP_D;
        if (p0) {
            int pos  = off + __popcll(m0 & lm);
            int flat = n * NCM1 + (lane - 1);
            if (pos < CAP_D)
                kb[pos] = ((u64)__float_as_uint(s0) << 32) | (u32)(~(u32)flat);
        }
        if (p1) {
            int pos  = off + c0 + __popcll(m1 & lm);
            int flat = n * NCM1 + (64 + lane - 1);
            if (pos < CAP_D)
                kb[pos] = ((u64)__float_as_uint(s1) << 32) | (u32)(~(u32)flat);
        }
    }
}

// ---------------- per-image exclusive prefix scan of rowcnt -> rowoff, nsel ----------------
__global__ __launch_bounds__(1024) void k_scan(const int* __restrict__ rowcnt,
                                               int* __restrict__ rowoff,
                                               int* __restrict__ nsel) {
    __shared__ int s_wt[16];
    int b = blockIdx.x, tid = threadIdx.x;
    int lane = tid & 63, wid = tid >> 6;

    int4 c4 = *(const int4*)(rowcnt + (long)b * NP + tid * 4);
    int ts = c4.x + c4.y + c4.z + c4.w;
    int S = ts;
#pragma unroll
    for (int s = 1; s < 64; s <<= 1) { int o = __shfl_up(S, s); if (lane >= s) S += o; }
    if (lane == 63) s_wt[wid] = S;
    int exclw = S - ts;
    __syncthreads();
    int add = 0;
    for (int w = 0; w < wid; ++w) add += s_wt[w];
    int base = add + exclw;
    int* ro = rowoff + (long)b * NP + tid * 4;
    ro[0] = base;
    ro[1] = base + c4.x;
    ro[2] = base + c4.x + c4.y;
    ro[3] = base + c4.x + c4.y + c4.z;
    if (tid == 1023) nsel[b] = base + ts;
}

// ---------------- dual-rank radix select: blocks 0-15 -> MSEL-th, 16-31 -> NSORT-th ----------------
__global__ __launch_bounds__(1024) void k_select(const u64* __restrict__ dense,
                                                 const int* __restrict__ nsel,
                                                 u64* __restrict__ Tsel,
                                                 u64* __restrict__ Tsel2) {
    __shared__ int hist[2048];
    __shared__ int s_sel, s_gt;
    int blk = blockIdx.x;
    int b   = blk & (BDIM - 1);
    int rank = (blk < BDIM) ? MSEL : NSORT;
    u64* dst = (blk < BDIM) ? (Tsel + b) : (Tsel2 + b);
    int tid = threadIdx.x;
    int n = nsel[b]; if (n > CAP_D) n = CAP_D;
    if (n <= rank) { if (tid == 0) *dst = 0ull; return; }

    const u64* kb = dense + (long)b * CAP_D;
    u64 prefix = 0, mask = 0;
    const int shifts[6] = {53, 42, 31, 20, 10, 0};
    const int bitsv [6] = {11, 11, 11, 11, 10, 10};

    for (int pass = 0; pass < 6; ++pass) {
        int shift = shifts[pass];
        int nb = 1 << bitsv[pass];
        if (tid < nb) hist[tid] = 0;
        if (tid + 1024 < nb) hist[tid + 1024] = 0;
        __syncthreads();
        for (int i = tid; i < n; i += 1024) {
            u64 k = kb[i];
            if ((k & mask) == prefix)
                atomicAdd(&hist[(int)((k >> shift) & (u64)(nb - 1))], 1);
        }
        __syncthreads();
        // suffix sum: hist[j] = count of elements in bins >= j
        for (int d = 1; d < nb; d <<= 1) {
            int v0 = 0, v1 = 0;
            if (tid < nb && tid + d < nb) v0 = hist[tid + d];
            if (tid + 1024 < nb && tid + 1024 + d < nb) v1 = hist[tid + 1024 + d];
            __syncthreads();
            if (tid < nb) hist[tid] += v0;
            if (tid + 1024 < nb) hist[tid + 1024] += v1;
            __syncthreads();
        }
        for (int j = tid; j < nb; j += 1024) {
            int c  = hist[j];
            int cn = (j + 1 < nb) ? hist[j + 1] : 0;
            if (c >= rank && cn < rank) { s_sel = j; s_gt = cn; }
        }
        __syncthreads();
        prefix |= ((u64)s_sel) << shift;
        mask   |= ((u64)(nb - 1)) << shift;
        rank   -= s_gt;
        __syncthreads();
    }
    if (tid == 0) *dst = prefix;
}

// ---------------- gather + sort(top-1024) + decode + sorted-walk NMS (+exact fallback) ----------------
__global__ __launch_bounds__(TN) void k_nms(const u64* __restrict__ dense,
                                            const int* __restrict__ nsel,
                                            const u64* __restrict__ Tsel,
                                            const u64* __restrict__ Tsel2,
                                            const float* __restrict__ boxreg,
                                            const float* __restrict__ props,
                                            float* __restrict__ out) {
    __shared__ u64 skey[MSEL];          // 32 KB keys (sorted desc per batch)
    __shared__ float4 sbox[MSEL];       // 64 KB raw clipped boxes
    __shared__ float2 spack[MSEL];      // 32 KB {offset-area, (float)label}
    __shared__ int s_cnt, s_nacc;

    int b = blockIdx.x, tid = threadIdx.x;
    int lane = tid & 63, wid = tid >> 6;
    int n = nsel[b]; if (n > CAP_D) n = CAP_D;
    u64 T  = Tsel[b];
    u64 T2 = Tsel2[b];
    const u64* kb = dense + (long)b * CAP_D;
    u64 lm = (1ull << lane) - 1ull;
    int npad = (n + TN - 1) & ~(TN - 1);

    // accepted list: distributed over wave-0 lane registers (2 slots/lane, <=128)
    float ax1_0 = 0, ay1_0 = 0, ax2_0 = 0, ay2_0 = 0, aar_0 = 0;
    float ax1_1 = 0, ay1_1 = 0, ax2_1 = 0, ay2_1 = 0, aar_1 = 0;
    int alb_0 = -1, alb_1 = -1;
    u64 aky_0 = 0, aky_1 = 0;
    int nacc = 0;

    for (int bt = 0; bt < 2; ++bt) {
        if (bt == 1) {
            if (s_nacc >= KOUT || T2 == 0ull) break;   // uniform (post-barrier)
        }
        int SZ = bt ? MSEL : NSORT;

        // ---- zero + wave-aggregated gather (round-7 verified pattern) ----
        for (int i = tid; i < SZ; i += TN) skey[i] = 0ull;
        if (tid == 0) s_cnt = 0;
        __syncthreads();
        for (int i0 = tid; i0 < npad; i0 += TN) {
            bool inb = (i0 < n);
            u64 k = inb ? kb[i0] : 0ull;
            bool pred = inb && (bt == 0 ? (k >= T2) : (k >= T && k < T2));
            u64 mb_ = __ballot(pred);
            int cnt = __popcll(mb_);
            int bp = 0;
            if (lane == 0 && cnt) bp = atomicAdd(&s_cnt, cnt);
            bp = __shfl(bp, 0);
            if (pred) {
                int pos = bp + __popcll(mb_ & lm);
                if (pos < SZ) skey[pos] = k;
            }
        }
        __syncthreads();
        int mb = s_cnt; if (mb > SZ) mb = SZ;

        // ---- sort descending (zeros sink to end) ----
        if (bt == 0) {
            // register bitonic, 1 element/thread; shfl for j<64, LDS for j>=64
            u64 r = skey[tid];
            for (int kk = 2; kk <= NSORT; kk <<= 1) {
                for (int j = kk >> 1; j; j >>= 1) {
                    u64 p;
                    if (j >= 64) {
                        skey[tid] = r;
                        __syncthreads();
                        p = skey[tid ^ j];
                        __syncthreads();
                    } else {
                        p = __shfl_xor(r, j);
                    }
                    bool lower = (tid & j) == 0;
                    bool desc  = ((tid & kk) == 0);
                    u64 mx = (r > p) ? r : p;
                    u64 mn = (r > p) ? p : r;
                    r = (lower == desc) ? mx : mn;
                }
            }
            skey[tid] = r;
            __syncthreads();
        } else {
            // LDS bitonic over MSEL (round-7 verified)
            for (int kk = 2; kk <= MSEL; kk <<= 1) {
                for (int j = kk >> 1; j > 0; j >>= 1) {
                    for (int t = tid; t < MSEL; t += TN) {
                        int l = t ^ j;
                        if (l > t) {
                            u64 a = skey[t], c = skey[l];
                            bool up = ((t & kk) == 0);
                            bool sw = up ? (a < c) : (a > c);
                            if (sw) { skey[t] = c; skey[l] = a; }
                        }
                    }
                    __syncthreads();
                }
            }
        }

        // ---- decode sorted candidates (round-6/7 verified expressions) ----
        for (int i = tid; i < mb; i += TN) {
            u64 k = skey[i];
            int flat = (int)(~(u32)k);
            int nidx = flat / NCM1;
            int c    = flat - nidx * NCM1 + 1;
            const float* pr = props + ((long)b * NP + nidx) * 4;
            float x1 = pr[0], y1 = pr[1], x2 = pr[2], y2 = pr[3];
            float w = x2 - x1, h = y2 - y1;
            float cx = x1 + 0.5f * w, cy = y1 + 0.5f * h;
            const float* rr = boxreg + (((long)b * NP + nidx) * NC + c) * 4;
            float dx = rr[0] / 10.0f, dy = rr[1] / 10.0f;
            float dw = fminf(rr[2] / 5.0f, DW_CLAMP_F);
            float dh = fminf(rr[3] / 5.0f, DW_CLAMP_F);
            // avoid FMA contraction: numpy does separate mul + add
            float pcx = __fadd_rn(__fmul_rn(dx, w), cx);
            float pcy = __fadd_rn(__fmul_rn(dy, h), cy);
            float pw  = __fmul_rn(expf(dw), w);
            float ph2 = __fmul_rn(expf(dh), h);
            float bx1 = fminf(fmaxf(pcx - 0.5f * pw, 0.0f), WF);
            float by1 = fminf(fmaxf(pcy - 0.5f * ph2, 0.0f), HF);
            float bx2 = fminf(fmaxf(pcx + 0.5f * pw, 0.0f), WF);
            float by2 = fminf(fmaxf(pcy + 0.5f * ph2, 0.0f), HF);
            sbox[i] = make_float4(bx1, by1, bx2, by2);
            // area on class-offset coords, exactly as reference computes it
            float offB = (float)c * OFFSETF;
            float ox1 = bx1 + offB, oy1 = by1 + offB;
            float ox2 = bx2 + offB, oy2 = by2 + offB;
            spack[i] = make_float2((ox2 - ox1) * (oy2 - oy1), (float)c);
        }
        __syncthreads();

        // ---- serial walk in sorted order (wave 0; register accepted list) ----
        if (wid == 0) {
            float4 Bv = sbox[0];
            float2 pk = spack[0];
            u64    ck = skey[0];
            for (int i = 0; i < mb && nacc < KOUT; ++i) {
                int ip = (i + 1 < mb) ? i + 1 : i;
                float4 nBv = sbox[ip];          // prefetch next candidate
                float2 npk = spack[ip];
                u64    nck = skey[ip];

                float areaB = pk.x;
                float labf  = pk.y;
                float off   = __fmul_rn(labf, OFFSETF);
                bool conf = false;
                // slot 0 (accepted index = lane)
                if (lane < nacc && (float)alb_0 == labf) {
                    float op1x = __fadd_rn(fminf(ax2_0, Bv.z), off);
                    float op2x = __fadd_rn(fmaxf(ax1_0, Bv.x), off);
                    float iw = fmaxf(op1x - op2x, 0.0f);
                    float op1y = __fadd_rn(fminf(ay2_0, Bv.w), off);
                    float op2y = __fadd_rn(fmaxf(ay1_0, Bv.y), off);
                    float ih = fmaxf(op1y - op2y, 0.0f);
                    float inter = iw * ih;
                    float denom = areaB + aar_0 - inter + 1e-9f;
                    if (inter / denom > NMS_T) conf = true;
                }
                // slot 1 (accepted index = 64 + lane)
                if (64 + lane < nacc && (float)alb_1 == labf) {
                    float op1x = __fadd_rn(fminf(ax2_1, Bv.z), off);
                    float op2x = __fadd_rn(fmaxf(ax1_1, Bv.x), off);
                    float iw = fmaxf(op1x - op2x, 0.0f);
                    float op1y = __fadd_rn(fminf(ay2_1, Bv.w), off);
                    float op2y = __fadd_rn(fmaxf(ay1_1, Bv.y), off);
                    float ih = fmaxf(op1y - op2y, 0.0f);
                    float inter = iw * ih;
                    float denom = areaB + aar_1 - inter + 1e-9f;
                    if (inter / denom > NMS_T) conf = true;
                }
                if (__ballot(conf) == 0ull) {        // accept (uniform)
                    if (nacc < 64) {
                        if (lane == nacc) {
                            ax1_0 = Bv.x; ay1_0 = Bv.y; ax2_0 = Bv.z; ay2_0 = Bv.w;
                            aar_0 = areaB; alb_0 = (int)labf; aky_0 = ck;
                        }
                    } else {
                        if (lane == nacc - 64) {
                            ax1_1 = Bv.x; ay1_1 = Bv.y; ax2_1 = Bv.z; ay2_1 = Bv.w;
                            aar_1 = areaB; alb_1 = (int)labf; aky_1 = ck;
                        }
                    }
                    ++nacc;
                }
                Bv = nBv; pk = npk; ck = nck;
            }
            if (lane == 0) s_nacc = nacc;
        }
        __syncthreads();
    }

    // ---- emit outputs in acceptance order ----
    int na = s_nacc; if (na > KOUT) na = KOUT;
    if (wid == 0) {
        if (lane < na) {
            int a = lane;
            float* ob = out + ((long)b * KOUT + a) * 4;
            ob[0] = ax1_0; ob[1] = ay1_0; ob[2] = ax2_0; ob[3] = ay2_0;
            out[BDIM * KOUT * 4 + b * KOUT + a] = __uint_as_float((u32)(aky_0 >> 32));
            out[BDIM * KOUT * 5 + b * KOUT + a] = (float)alb_0;
            out[BDIM * KOUT * 6 + b * KOUT + a] = 1.0f;
        }
        if (64 + lane < na) {
            int a = 64 + lane;
            float* ob = out + ((long)b * KOUT + a) * 4;
            ob[0] = ax1_1; ob[1] = ay1_1; ob[2] = ax2_1; ob[3] = ay2_1;
            out[BDIM * KOUT * 4 + b * KOUT + a] = __uint_as_float((u32)(aky_1 >> 32));
            out[BDIM * KOUT * 5 + b * KOUT + a] = (float)alb_1;
            out[BDIM * KOUT * 6 + b * KOUT + a] = 1.0f;
        }
    }
    for (int a = tid; a < KOUT; a += TN) {
        if (a >= na) {
            float* ob = out + ((long)b * KOUT + a) * 4;
            ob[0] = 0.0f; ob[1] = 0.0f; ob[2] = 0.0f; ob[3] = 0.0f;
            out[BDIM * KOUT * 4 + b * KOUT + a] = 0.0f;
            out[BDIM * KOUT * 5 + b * KOUT + a] = -1.0f;
            out[BDIM * KOUT * 6 + b * KOUT + a] = 0.0f;
        }
    }
}

extern "C" void kernel_launch(void* const* d_in, const int* in_sizes, int n_in,
                              void* d_out, int out_size, void* d_ws, size_t ws_size,
                              hipStream_t stream) {
    const float* logits = (const float*)d_in[0];
    const float* boxreg = (const float*)d_in[1];
    const float* props  = (const float*)d_in[2];
    float* out = (float*)d_out;

    char* ws = (char*)d_ws;
    int* rowcnt = (int*)(ws + 0);                 // 256 KB
    int* rowoff = (int*)(ws + 262144);            // 256 KB
    int* nsel   = (int*)(ws + 524288);            // 64 B
    u64* Tsel   = (u64*)(ws + 525312);            // 128 B
    u64* Tsel2  = (u64*)(ws + 525824);            // 128 B
    u64* dense  = (u64*)(ws + 526336);            // 16*40960*8 = 5.24 MB

    k_soft<0><<<(BDIM * NP) / 4, 256, 0, stream>>>(logits, rowcnt, nullptr, nullptr);
    k_scan<<<BDIM, 1024, 0, stream>>>(rowcnt, rowoff, nsel);
    k_soft<1><<<(BDIM * NP) / 4, 256, 0, stream>>>(logits, rowcnt, rowoff, dense);
    k_select<<<2 * BDIM, 1024, 0, stream>>>(dense, nsel, Tsel, Tsel2);
    k_nms<<<BDIM, TN, 0, stream>>>(dense, nsel, Tsel, Tsel2, boxreg, props, out);
}